// Round 12
// baseline (361.325 us; speedup 1.0000x reference)
//
#include <hip/hip_runtime.h>

// ---------------- problem constants ----------------
constexpr int N_NODES = 50000;
constexpr int N_EDGES = 800000;
constexpr int F_INPUT = 96;
constexpr int HID = 128;
constexpr int NCLS = 40;
// bucket record per node: 64 ushorts = 128B. [0:2) = int counter, [2:64) = 62 entries.
// P(Poisson(16) > 62) ~ 2e-18 -> drop risk negligible; guarded anyway.
constexpr int REC = 64;   // ushorts per node record
constexpr int ENT = 62;   // payload capacity

typedef __attribute__((ext_vector_type(8))) short short8;
typedef __attribute__((ext_vector_type(4))) float f32x4;

// ---------------- bf16 helpers ----------------
__device__ __forceinline__ float bf2f(unsigned int u16) {
    unsigned int x = u16 << 16;
    return __builtin_bit_cast(float, x);
}
__device__ __forceinline__ unsigned short f2bf(float f) {  // round-to-nearest-even
    unsigned int x = __builtin_bit_cast(unsigned int, f);
    x += 0x7fffu + ((x >> 16) & 1u);
    return (unsigned short)(x >> 16);
}

// ---------------- merged prep (no graph atomics here anymore) ----------------
// blocks: [0,4688) x->bf16 4 elem/thr | [4688,5470) dst->ushort compress 4/thr |
//         [5470,5503) fuse_w | [5503,5551) W1aT | [5551,5615) W2aT | [5615,5679) W1bT
constexpr int PA_XC = (N_NODES * F_INPUT / 4 + 255) / 256;   // 4688
constexpr int PA_DC = (N_EDGES / 4 + 255) / 256;             // 782
constexpr int PA_D0 = PA_XC;           // 4688
constexpr int PA_F0 = PA_D0 + PA_DC;   // 5470
constexpr int PA_W1 = PA_F0 + 33;      // 5503
constexpr int PA_W2 = PA_W1 + 48;      // 5551
constexpr int PA_W3 = PA_W2 + 64;      // 5615
constexpr int PA_END = PA_W3 + 64;     // 5679

__global__ __launch_bounds__(256) void prep_all(
    const float* __restrict__ x,
    const float* __restrict__ W1a, const float* __restrict__ W2a,
    const float* __restrict__ W1b, const float* __restrict__ W2b,
    const float* __restrict__ b2b, const float* __restrict__ Wfc,
    const float* __restrict__ bfc, const int* __restrict__ ei,
    unsigned short* __restrict__ W1aT, unsigned short* __restrict__ W2aT,
    unsigned short* __restrict__ W1bT, unsigned short* __restrict__ WcT,
    float* __restrict__ bc, unsigned short* __restrict__ dstc,
    unsigned short* __restrict__ xb) {
    const int b = blockIdx.x;
    const int tid = threadIdx.x;
    if (b < PA_D0) {
        int e4 = (b * 256 + tid) * 4;
        if (e4 < N_NODES * F_INPUT) {
            float4 v = *reinterpret_cast<const float4*>(&x[e4]);
            uint2 o;
            o.x = (unsigned int)f2bf(v.x) | ((unsigned int)f2bf(v.y) << 16);
            o.y = (unsigned int)f2bf(v.z) | ((unsigned int)f2bf(v.w) << 16);
            *reinterpret_cast<uint2*>(&xb[e4]) = o;
        }
    } else if (b < PA_F0) {
        int e4 = ((b - PA_D0) * 256 + tid) * 4;
        if (e4 < N_EDGES) {
            int4 d = *reinterpret_cast<const int4*>(&ei[N_EDGES + e4]);
            uint2 o;
            o.x = (unsigned int)(unsigned short)d.x | ((unsigned int)(unsigned short)d.y << 16);
            o.y = (unsigned int)(unsigned short)d.z | ((unsigned int)(unsigned short)d.w << 16);
            *reinterpret_cast<uint2*>(&dstc[e4]) = o;
        }
    } else if (b < PA_W1) {
        int idx = (b - PA_F0) * 256 + tid;
        if (idx < 64 * 128) {
            int n = idx >> 7, k = idx & 127;
            float s = 0.f;
            if (n < NCLS) {
                for (int j = 0; j < 128; ++j) s += W2b[k * 128 + j] * Wfc[j * NCLS + n];
            }
            WcT[idx] = f2bf(s);
        } else if (idx < 64 * 128 + 64) {
            int n = idx - 64 * 128;
            float s = 0.f;
            if (n < NCLS) {
                s = bfc[n];
                for (int j = 0; j < 128; ++j) s += b2b[j] * Wfc[j * NCLS + n];
            }
            bc[n] = s;
        }
    } else if (b < PA_W2) {
        int idx = (b - PA_W1) * 256 + tid;  // 12288 = 128 cols x 96 k
        int n = idx / 96, k = idx % 96;
        W1aT[idx] = f2bf(W1a[k * 128 + n]);
    } else if (b < PA_W3) {
        int idx = (b - PA_W2) * 256 + tid;  // 16384
        int n = idx >> 7, k = idx & 127;
        W2aT[idx] = f2bf(W2a[k * 128 + n]);
    } else {
        int idx = (b - PA_W3) * 256 + tid;
        int n = idx >> 7, k = idx & 127;
        W1bT[idx] = f2bf(W1b[k * 128 + n]);
    }
}

// ---------------- atomic-free bucket fill: node-partitioned scan + LDS counters --------
// 256 blocks x 1024 thr; block owns nodes [b*196, b*196+196). Scans the packed dst
// array (1.6MB, L2-resident), LDS-atomics for in-range edges only (~3.1K/block),
// writes payload + final counters. NO global atomics, NO memset needed.
// Slot order within a record is nondeterministic (LDS atomic races) — gather's
// bitonic sort canonicalizes; content SET is deterministic.
__global__ __launch_bounds__(1024) void fill_scan(const int* __restrict__ ei,
                                                  const unsigned int* __restrict__ dstc2,
                                                  unsigned short* __restrict__ bucket) {
    constexpr int NPB = (N_NODES + 255) / 256;  // 196 nodes per block
    __shared__ int lcnt[NPB];
    const int base = blockIdx.x * NPB;
    const int nloc = min(NPB, N_NODES - base);
    for (int i = threadIdx.x; i < NPB; i += 1024) lcnt[i] = 0;
    __syncthreads();
    constexpr int NU = N_EDGES / 2;  // 400000 packed pairs
    for (int u = threadIdx.x; u < NU; u += 1024) {
        unsigned int pk = dstc2[u];
        int e0 = u * 2;
        int d0 = (int)(pk & 0xffffu), d1 = (int)(pk >> 16);
        int r0 = d0 - base, r1 = d1 - base;
        if ((unsigned)r0 < (unsigned)nloc) {
            int pos = atomicAdd(&lcnt[r0], 1);
            if (pos < ENT) bucket[(size_t)d0 * REC + 2 + pos] = (unsigned short)ei[e0];
        }
        if ((unsigned)r1 < (unsigned)nloc) {
            int pos = atomicAdd(&lcnt[r1], 1);
            if (pos < ENT) bucket[(size_t)d1 * REC + 2 + pos] = (unsigned short)ei[e0 + 1];
        }
    }
    __syncthreads();
    for (int i = threadIdx.x; i < nloc; i += 1024) {
        int c = lcnt[i];
        *reinterpret_cast<int*>(&bucket[(size_t)(base + i) * REC]) = (c > ENT ? ENT : c);
    }
}

// ---------------- gather (bf16 rows): OUT[n] = X[n] + sum nbrs (SORTED order) ----------------
// one wave per node. Record loaded one entry/lane, bitonic-sorted across the wave
// (canonical ascending order -> deterministic f32 accumulation regardless of the
// racey fill order), then neighbors broadcast via __shfl.
template<int F>
__global__ __launch_bounds__(256) void gather_bf(const unsigned short* __restrict__ X,
                                                 const unsigned short* __restrict__ bucket,
                                                 unsigned short* __restrict__ OUT) {
    const int wave = threadIdx.x >> 6;
    const int lane = threadIdx.x & 63;
    const int node = blockIdx.x * 4 + wave;
    if (node >= N_NODES) return;
    const unsigned short* rec = &bucket[(size_t)node * REC];
    int deg = *reinterpret_cast<const int*>(rec);
    if (deg > ENT) deg = ENT;

    // load payload entry for this lane (coalesced within the 128B record)
    int v = (lane < deg) ? (int)rec[2 + lane] : 0x7fffffff;
    // full 64-lane bitonic sort, ascending
#pragma unroll
    for (int k = 2; k <= 64; k <<= 1) {
#pragma unroll
        for (int j = k >> 1; j > 0; j >>= 1) {
            int pv = __shfl_xor(v, j, 64);
            bool keepmin = (((lane & k) == 0) == ((lane & j) == 0));
            v = keepmin ? (pv < v ? pv : v) : (pv > v ? pv : v);
        }
    }

    const int f = lane * 2;
    const bool act = (f < F);
    float a0 = 0.f, a1 = 0.f;
    int j = 0;
    for (; j + 7 < deg; j += 8) {
        int s[8];
        unsigned int vv[8];
#pragma unroll
        for (int q = 0; q < 8; ++q) s[q] = __shfl(v, j + q, 64);
#pragma unroll
        for (int q = 0; q < 8; ++q) {
            if (act) vv[q] = *reinterpret_cast<const unsigned int*>(&X[(size_t)s[q] * F + f]);
        }
        if (act) {
#pragma unroll
            for (int q = 0; q < 8; ++q) {
                a0 += bf2f(vv[q] & 0xffff);
                a1 += bf2f(vv[q] >> 16);
            }
        }
    }
    if (j + 3 < deg) {
        int s[4];
        unsigned int vv[4];
#pragma unroll
        for (int q = 0; q < 4; ++q) s[q] = __shfl(v, j + q, 64);
#pragma unroll
        for (int q = 0; q < 4; ++q) {
            if (act) vv[q] = *reinterpret_cast<const unsigned int*>(&X[(size_t)s[q] * F + f]);
        }
        if (act) {
#pragma unroll
            for (int q = 0; q < 4; ++q) {
                a0 += bf2f(vv[q] & 0xffff);
                a1 += bf2f(vv[q] >> 16);
            }
        }
        j += 4;
    }
    for (; j < deg; ++j) {
        int s = __shfl(v, j, 64);
        if (act) {
            unsigned int vx = *reinterpret_cast<const unsigned int*>(&X[(size_t)s * F + f]);
            a0 += bf2f(vx & 0xffff);
            a1 += bf2f(vx >> 16);
        }
    }
    if (act) {
        unsigned int xv = *reinterpret_cast<const unsigned int*>(&X[(size_t)node * F + f]);
        a0 += bf2f(xv & 0xffff);
        a1 += bf2f(xv >> 16);
        unsigned int o = (unsigned int)f2bf(a0) | ((unsigned int)f2bf(a1) << 16);
        *reinterpret_cast<unsigned int*>(&OUT[(size_t)node * F + f]) = o;
    }
}

// ---------------- fused 2-layer MLP via MFMA + per-wave LDS tile ----------------
// out = act2(relu(A@W1T^T + b1) @ W2T^T + b2); A bf16 [M][K1], W1T [128][K1], W2T [NT2*16][128].
// 256 thr = 4 waves; block = 64 rows; wave = 16 rows. h1 tile (16x128 bf16) bounced
// through per-wave LDS [16][136] (136*2B keeps 16B row alignment for b128 reads).
template<int K1, int NT2, int NCOUT, bool RELU2, bool BF16_OUT>
__global__ __launch_bounds__(256) void mlp_fused(const unsigned short* __restrict__ A,
                                                 const unsigned short* __restrict__ W1T,
                                                 const float* __restrict__ b1,
                                                 const unsigned short* __restrict__ W2T,
                                                 const float* __restrict__ b2,
                                                 void* __restrict__ Cout, int M) {
    constexpr int KS1 = K1 / 32;
    constexpr int NT1 = 8;   // hidden = 128 cols
    constexpr int K2 = 128;
    constexpr int KS2 = K2 / 32;
    __shared__ __align__(16) unsigned short sH[4][16][136];

    const int tid = threadIdx.x;
    const int lane = tid & 63;
    const int wv = tid >> 6;
    const int rowbase = blockIdx.x * 64 + wv * 16;
    const int rA = lane & 15;
    const int kg = lane >> 4;

    int r0 = rowbase + rA;
    if (r0 >= M) r0 = M - 1;  // clamp; stores guarded
    const unsigned short* ap = A + (size_t)r0 * K1 + kg * 8;
    const unsigned short* b1p = W1T + (size_t)rA * K1 + kg * 8;

    f32x4 acc1[NT1] = {};
#pragma unroll
    for (int ks = 0; ks < KS1; ++ks) {
        short8 a = *reinterpret_cast<const short8*>(ap + ks * 32);
#pragma unroll
        for (int nt = 0; nt < NT1; ++nt) {
            short8 b = *reinterpret_cast<const short8*>(b1p + nt * 16 * K1 + ks * 32);
            acc1[nt] = __builtin_amdgcn_mfma_f32_16x16x32_bf16(a, b, acc1[nt], 0, 0, 0);
        }
    }

    const int oc = lane & 15;
    const int orow = (lane >> 4) * 4;  // D-layout: row=(lane>>4)*4+reg, col=lane&15
#pragma unroll
    for (int nt = 0; nt < NT1; ++nt) {
        float bz = b1[nt * 16 + oc];
#pragma unroll
        for (int r = 0; r < 4; ++r) {
            float v = fmaxf(acc1[nt][r] + bz, 0.f);
            sH[wv][orow + r][nt * 16 + oc] = f2bf(v);
        }
    }
    __syncthreads();

    const unsigned short* b2p = W2T + (size_t)rA * K2 + kg * 8;
    f32x4 acc2[NT2] = {};
#pragma unroll
    for (int ks = 0; ks < KS2; ++ks) {
        short8 a = *reinterpret_cast<const short8*>(&sH[wv][rA][kg * 8 + ks * 32]);
#pragma unroll
        for (int nt = 0; nt < NT2; ++nt) {
            short8 b = *reinterpret_cast<const short8*>(b2p + nt * 16 * K2 + ks * 32);
            acc2[nt] = __builtin_amdgcn_mfma_f32_16x16x32_bf16(a, b, acc2[nt], 0, 0, 0);
        }
    }

#pragma unroll
    for (int nt = 0; nt < NT2; ++nt) {
        int col = nt * 16 + oc;
        if (col >= NCOUT) continue;
        float bz = b2[col];
#pragma unroll
        for (int r = 0; r < 4; ++r) {
            int row = rowbase + orow + r;
            if (row < M) {
                float v = acc2[nt][r] + bz;
                if (RELU2) v = fmaxf(v, 0.f);
                if (BF16_OUT)
                    ((unsigned short*)Cout)[(size_t)row * NCOUT + col] = f2bf(v);
                else
                    ((float*)Cout)[(size_t)row * NCOUT + col] = v;
            }
        }
    }
}

// ---------------- launch ----------------
extern "C" void kernel_launch(void* const* d_in, const int* in_sizes, int n_in,
                              void* d_out, int out_size, void* d_ws, size_t ws_size,
                              hipStream_t stream) {
    const float* x   = (const float*)d_in[0];
    const int*   ei  = (const int*)d_in[1];
    const float* W1a = (const float*)d_in[2];
    const float* b1a = (const float*)d_in[3];
    const float* W2a = (const float*)d_in[4];
    const float* b2a = (const float*)d_in[5];
    const float* W1b = (const float*)d_in[6];
    const float* b1b = (const float*)d_in[7];
    const float* W2b = (const float*)d_in[8];
    const float* b2b = (const float*)d_in[9];
    const float* Wfc = (const float*)d_in[10];
    const float* bfc = (const float*)d_in[11];
    float* out = (float*)d_out;

    char* p = (char*)d_ws;
    auto alloc = [&](size_t bytes) {
        char* r = p;
        p += (bytes + 255) & ~size_t(255);
        return r;
    };
    unsigned short* xb   = (unsigned short*)alloc((size_t)N_NODES * F_INPUT * 2);
    unsigned short* h0   = (unsigned short*)alloc((size_t)N_NODES * F_INPUT * 2);
    unsigned short* t    = (unsigned short*)alloc((size_t)N_NODES * HID * 2);
    unsigned short* g    = (unsigned short*)alloc((size_t)N_NODES * HID * 2);
    unsigned short* W1aT = (unsigned short*)alloc(128 * 96 * 2);
    unsigned short* W2aT = (unsigned short*)alloc(128 * 128 * 2);
    unsigned short* W1bT = (unsigned short*)alloc(128 * 128 * 2);
    unsigned short* WcT  = (unsigned short*)alloc(64 * 128 * 2);
    float* bc            = (float*)alloc(64 * 4);
    unsigned short* dstc = (unsigned short*)alloc((size_t)N_EDGES * 2);         // 1.6MB
    unsigned short* bucket = (unsigned short*)alloc((size_t)N_NODES * REC * 2); // 6.4MB

    const int nb4 = (N_NODES + 3) / 4;  // 12500
    const int mb = (N_NODES + 63) / 64; // 782

    // prep: x->bf16 + dst compress + fuse_w + weight transposes (pure BW, no atomics)
    prep_all<<<PA_END, 256, 0, stream>>>(x, W1a, W2a, W1b, W2b, b2b, Wfc, bfc, ei,
                                         W1aT, W2aT, W1bT, WcT, bc, dstc, xb);

    // atomic-free bucket fill (writes counters itself; no memset anywhere)
    fill_scan<<<256, 1024, 0, stream>>>(ei, (const unsigned int*)dstc, bucket);

    // GIN layer 1: gather on bf16 x, then fused MLP (relu between, relu after)
    gather_bf<F_INPUT><<<nb4, 256, 0, stream>>>(xb, bucket, h0);
    mlp_fused<96, 8, 128, true, true><<<mb, 256, 0, stream>>>(h0, W1aT, b1a, W2aT, b2a, t,
                                                              N_NODES);

    // GIN layer 2: gather, then fused MLP (relu between, final linear folded W2b@Wfc)
    gather_bf<HID><<<nb4, 256, 0, stream>>>(t, bucket, g);
    mlp_fused<128, 4, 40, false, false><<<mb, 256, 0, stream>>>(g, W1bT, b1b, WcT, bc, out,
                                                                N_NODES);
}

// Round 13
// 232.842 us; speedup vs baseline: 1.5518x; 1.5518x over previous
//
#include <hip/hip_runtime.h>

// ---------------- problem constants ----------------
constexpr int N_NODES = 50000;
constexpr int N_EDGES = 800000;
constexpr int F_INPUT = 96;
constexpr int HID = 128;
constexpr int NCLS = 40;
// bucket record per node: 64 ushorts = 128B. [0:2) = int counter, [2:64) = 62 entries.
constexpr int REC = 64;   // ushorts per node record
constexpr int ENT = 62;   // payload capacity; P(Poisson(16) > 62) ~ 2e-18
// radix partition: bin = dst>>8 (256 nodes/bin), 196 bins
constexpr int NBIN = 196;
constexpr int CAPB = 4608;  // bin capacity; mean 4096, +8 sigma

typedef __attribute__((ext_vector_type(8))) short short8;
typedef __attribute__((ext_vector_type(4))) float f32x4;

// ---------------- bf16 helpers ----------------
__device__ __forceinline__ float bf2f(unsigned int u16) {
    unsigned int x = u16 << 16;
    return __builtin_bit_cast(float, x);
}
__device__ __forceinline__ unsigned short f2bf(float f) {  // round-to-nearest-even
    unsigned int x = __builtin_bit_cast(unsigned int, f);
    x += 0x7fffu + ((x >> 16) & 1u);
    return (unsigned short)(x >> 16);
}

// ---------------- merged prep ----------------
// blocks: [0,391) radix pass 1 (8 edges/thr) | [391,5079) x->bf16 4/thr |
//         [5079,5112) fuse_w | [5112,5160) W1aT | [5160,5224) W2aT | [5224,5288) W1bT
// binCursor[NBIN] must be pre-zeroed (784B memset).
constexpr int PA_R1 = 391;                                  // ceil(800K/2048)
constexpr int PA_XC = (N_NODES * F_INPUT / 4 + 255) / 256;  // 4688
constexpr int PA_F0 = PA_R1 + PA_XC;   // 5079
constexpr int PA_W1 = PA_F0 + 33;      // 5112
constexpr int PA_W2 = PA_W1 + 48;      // 5160
constexpr int PA_W3 = PA_W2 + 64;      // 5224
constexpr int PA_END = PA_W3 + 64;     // 5288

__global__ __launch_bounds__(256) void prep_all(
    const float* __restrict__ x,
    const float* __restrict__ W1a, const float* __restrict__ W2a,
    const float* __restrict__ W1b, const float* __restrict__ W2b,
    const float* __restrict__ b2b, const float* __restrict__ Wfc,
    const float* __restrict__ bfc, const int* __restrict__ ei,
    unsigned short* __restrict__ W1aT, unsigned short* __restrict__ W2aT,
    unsigned short* __restrict__ W1bT, unsigned short* __restrict__ WcT,
    float* __restrict__ bc, int* __restrict__ binCursor,
    unsigned int* __restrict__ binBuf, unsigned short* __restrict__ xb) {
    const int b = blockIdx.x;
    const int tid = threadIdx.x;
    if (b < PA_R1) {
        // radix pass 1: partition edges into 196 dst-range bins.
        __shared__ int cnt[NBIN];
        __shared__ int base[NBIN];
        for (int i = tid; i < NBIN; i += 256) cnt[i] = 0;
        __syncthreads();
        int binq[8], posq[8];
        unsigned int recq[8];
#pragma unroll
        for (int q = 0; q < 8; ++q) {
            int e = b * 2048 + q * 256 + tid;
            binq[q] = -1;
            if (e < N_EDGES) {
                int src = ei[e], dst = ei[N_EDGES + e];
                int bin = dst >> 8;
                binq[q] = bin;
                recq[q] = (unsigned int)(src & 0xffff) | ((unsigned int)(dst & 255) << 16);
                posq[q] = atomicAdd(&cnt[bin], 1);
            }
        }
        __syncthreads();
        for (int i = tid; i < NBIN; i += 256)
            base[i] = (cnt[i] > 0) ? atomicAdd(&binCursor[i], cnt[i]) : 0;
        __syncthreads();
#pragma unroll
        for (int q = 0; q < 8; ++q) {
            if (binq[q] >= 0) {
                int off = base[binq[q]] + posq[q];
                if (off < CAPB) binBuf[(size_t)binq[q] * CAPB + off] = recq[q];
            }
        }
    } else if (b < PA_F0) {
        int e4 = ((b - PA_R1) * 256 + tid) * 4;
        if (e4 < N_NODES * F_INPUT) {
            float4 v = *reinterpret_cast<const float4*>(&x[e4]);
            uint2 o;
            o.x = (unsigned int)f2bf(v.x) | ((unsigned int)f2bf(v.y) << 16);
            o.y = (unsigned int)f2bf(v.z) | ((unsigned int)f2bf(v.w) << 16);
            *reinterpret_cast<uint2*>(&xb[e4]) = o;
        }
    } else if (b < PA_W1) {
        int idx = (b - PA_F0) * 256 + tid;
        if (idx < 64 * 128) {
            int n = idx >> 7, k = idx & 127;
            float s = 0.f;
            if (n < NCLS) {
                for (int j = 0; j < 128; ++j) s += W2b[k * 128 + j] * Wfc[j * NCLS + n];
            }
            WcT[idx] = f2bf(s);
        } else if (idx < 64 * 128 + 64) {
            int n = idx - 64 * 128;
            float s = 0.f;
            if (n < NCLS) {
                s = bfc[n];
                for (int j = 0; j < 128; ++j) s += b2b[j] * Wfc[j * NCLS + n];
            }
            bc[n] = s;
        }
    } else if (b < PA_W2) {
        int idx = (b - PA_W1) * 256 + tid;  // 12288 = 128 cols x 96 k
        int n = idx / 96, k = idx % 96;
        W1aT[idx] = f2bf(W1a[k * 128 + n]);
    } else if (b < PA_W3) {
        int idx = (b - PA_W2) * 256 + tid;  // 16384
        int n = idx >> 7, k = idx & 127;
        W2aT[idx] = f2bf(W2a[k * 128 + n]);
    } else {
        int idx = (b - PA_W3) * 256 + tid;
        int n = idx >> 7, k = idx & 127;
        W1bT[idx] = f2bf(W1b[k * 128 + n]);
    }
}

// ---------------- radix pass 2: bin -> bucket records (atomic-free globally) --------
// 196 blocks; block b owns nodes [b*256, b*256+256). Reads its bin (coalesced),
// LDS-counts, writes payload into the block-local 32KB bucket region + counters.
__global__ __launch_bounds__(1024) void radix2(const int* __restrict__ binCursor,
                                               const unsigned int* __restrict__ binBuf,
                                               unsigned short* __restrict__ bucket) {
    __shared__ int lcnt[256];
    const int bin = blockIdx.x;
    const int tid = threadIdx.x;
    for (int i = tid; i < 256; i += 1024) lcnt[i] = 0;
    __syncthreads();
    int n = binCursor[bin];
    if (n > CAPB) n = CAPB;
    for (int i = tid; i < n; i += 1024) {
        unsigned int r = binBuf[(size_t)bin * CAPB + i];
        int low = (int)(r >> 16);
        int pos = atomicAdd(&lcnt[low], 1);
        if (pos < ENT)
            bucket[(size_t)((bin << 8) + low) * REC + 2 + pos] = (unsigned short)(r & 0xffff);
    }
    __syncthreads();
    for (int i = tid; i < 256; i += 1024) {
        int node = (bin << 8) + i;
        if (node < N_NODES) {
            int c = lcnt[i];
            *reinterpret_cast<int*>(&bucket[(size_t)node * REC]) = (c > ENT ? ENT : c);
        }
    }
}

// ---------------- gather (bf16 rows): OUT[n] = X[n] + sum nbrs (SORTED order) ----------------
template<int F>
__global__ __launch_bounds__(256) void gather_bf(const unsigned short* __restrict__ X,
                                                 const unsigned short* __restrict__ bucket,
                                                 unsigned short* __restrict__ OUT) {
    const int wave = threadIdx.x >> 6;
    const int lane = threadIdx.x & 63;
    const int node = blockIdx.x * 4 + wave;
    if (node >= N_NODES) return;
    const unsigned short* rec = &bucket[(size_t)node * REC];
    int deg = *reinterpret_cast<const int*>(rec);
    if (deg > ENT) deg = ENT;

    int v = (lane < deg) ? (int)rec[2 + lane] : 0x7fffffff;
    // full 64-lane bitonic sort, ascending (canonical order -> deterministic sums)
#pragma unroll
    for (int k = 2; k <= 64; k <<= 1) {
#pragma unroll
        for (int j = k >> 1; j > 0; j >>= 1) {
            int pv = __shfl_xor(v, j, 64);
            bool keepmin = (((lane & k) == 0) == ((lane & j) == 0));
            v = keepmin ? (pv < v ? pv : v) : (pv > v ? pv : v);
        }
    }

    const int f = lane * 2;
    const bool act = (f < F);
    float a0 = 0.f, a1 = 0.f;
    int j = 0;
    for (; j + 7 < deg; j += 8) {
        int s[8];
        unsigned int vv[8];
#pragma unroll
        for (int q = 0; q < 8; ++q) s[q] = __shfl(v, j + q, 64);
#pragma unroll
        for (int q = 0; q < 8; ++q) {
            if (act) vv[q] = *reinterpret_cast<const unsigned int*>(&X[(size_t)s[q] * F + f]);
        }
        if (act) {
#pragma unroll
            for (int q = 0; q < 8; ++q) {
                a0 += bf2f(vv[q] & 0xffff);
                a1 += bf2f(vv[q] >> 16);
            }
        }
    }
    if (j + 3 < deg) {
        int s[4];
        unsigned int vv[4];
#pragma unroll
        for (int q = 0; q < 4; ++q) s[q] = __shfl(v, j + q, 64);
#pragma unroll
        for (int q = 0; q < 4; ++q) {
            if (act) vv[q] = *reinterpret_cast<const unsigned int*>(&X[(size_t)s[q] * F + f]);
        }
        if (act) {
#pragma unroll
            for (int q = 0; q < 4; ++q) {
                a0 += bf2f(vv[q] & 0xffff);
                a1 += bf2f(vv[q] >> 16);
            }
        }
        j += 4;
    }
    for (; j < deg; ++j) {
        int s = __shfl(v, j, 64);
        if (act) {
            unsigned int vx = *reinterpret_cast<const unsigned int*>(&X[(size_t)s * F + f]);
            a0 += bf2f(vx & 0xffff);
            a1 += bf2f(vx >> 16);
        }
    }
    if (act) {
        unsigned int xv = *reinterpret_cast<const unsigned int*>(&X[(size_t)node * F + f]);
        a0 += bf2f(xv & 0xffff);
        a1 += bf2f(xv >> 16);
        unsigned int o = (unsigned int)f2bf(a0) | ((unsigned int)f2bf(a1) << 16);
        *reinterpret_cast<unsigned int*>(&OUT[(size_t)node * F + f]) = o;
    }
}

// ---------------- fused 2-layer MLP via MFMA + per-wave LDS tile ----------------
template<int K1, int NT2, int NCOUT, bool RELU2, bool BF16_OUT>
__global__ __launch_bounds__(256) void mlp_fused(const unsigned short* __restrict__ A,
                                                 const unsigned short* __restrict__ W1T,
                                                 const float* __restrict__ b1,
                                                 const unsigned short* __restrict__ W2T,
                                                 const float* __restrict__ b2,
                                                 void* __restrict__ Cout, int M) {
    constexpr int KS1 = K1 / 32;
    constexpr int NT1 = 8;   // hidden = 128 cols
    constexpr int K2 = 128;
    constexpr int KS2 = K2 / 32;
    __shared__ __align__(16) unsigned short sH[4][16][136];

    const int tid = threadIdx.x;
    const int lane = tid & 63;
    const int wv = tid >> 6;
    const int rowbase = blockIdx.x * 64 + wv * 16;
    const int rA = lane & 15;
    const int kg = lane >> 4;

    int r0 = rowbase + rA;
    if (r0 >= M) r0 = M - 1;  // clamp; stores guarded
    const unsigned short* ap = A + (size_t)r0 * K1 + kg * 8;
    const unsigned short* b1p = W1T + (size_t)rA * K1 + kg * 8;

    f32x4 acc1[NT1] = {};
#pragma unroll
    for (int ks = 0; ks < KS1; ++ks) {
        short8 a = *reinterpret_cast<const short8*>(ap + ks * 32);
#pragma unroll
        for (int nt = 0; nt < NT1; ++nt) {
            short8 b = *reinterpret_cast<const short8*>(b1p + nt * 16 * K1 + ks * 32);
            acc1[nt] = __builtin_amdgcn_mfma_f32_16x16x32_bf16(a, b, acc1[nt], 0, 0, 0);
        }
    }

    const int oc = lane & 15;
    const int orow = (lane >> 4) * 4;  // D-layout: row=(lane>>4)*4+reg, col=lane&15
#pragma unroll
    for (int nt = 0; nt < NT1; ++nt) {
        float bz = b1[nt * 16 + oc];
#pragma unroll
        for (int r = 0; r < 4; ++r) {
            float v = fmaxf(acc1[nt][r] + bz, 0.f);
            sH[wv][orow + r][nt * 16 + oc] = f2bf(v);
        }
    }
    __syncthreads();

    const unsigned short* b2p = W2T + (size_t)rA * K2 + kg * 8;
    f32x4 acc2[NT2] = {};
#pragma unroll
    for (int ks = 0; ks < KS2; ++ks) {
        short8 a = *reinterpret_cast<const short8*>(&sH[wv][rA][kg * 8 + ks * 32]);
#pragma unroll
        for (int nt = 0; nt < NT2; ++nt) {
            short8 b = *reinterpret_cast<const short8*>(b2p + nt * 16 * K2 + ks * 32);
            acc2[nt] = __builtin_amdgcn_mfma_f32_16x16x32_bf16(a, b, acc2[nt], 0, 0, 0);
        }
    }

#pragma unroll
    for (int nt = 0; nt < NT2; ++nt) {
        int col = nt * 16 + oc;
        if (col >= NCOUT) continue;
        float bz = b2[col];
#pragma unroll
        for (int r = 0; r < 4; ++r) {
            int row = rowbase + orow + r;
            if (row < M) {
                float v = acc2[nt][r] + bz;
                if (RELU2) v = fmaxf(v, 0.f);
                if (BF16_OUT)
                    ((unsigned short*)Cout)[(size_t)row * NCOUT + col] = f2bf(v);
                else
                    ((float*)Cout)[(size_t)row * NCOUT + col] = v;
            }
        }
    }
}

// ---------------- launch ----------------
extern "C" void kernel_launch(void* const* d_in, const int* in_sizes, int n_in,
                              void* d_out, int out_size, void* d_ws, size_t ws_size,
                              hipStream_t stream) {
    const float* x   = (const float*)d_in[0];
    const int*   ei  = (const int*)d_in[1];
    const float* W1a = (const float*)d_in[2];
    const float* b1a = (const float*)d_in[3];
    const float* W2a = (const float*)d_in[4];
    const float* b2a = (const float*)d_in[5];
    const float* W1b = (const float*)d_in[6];
    const float* b1b = (const float*)d_in[7];
    const float* W2b = (const float*)d_in[8];
    const float* b2b = (const float*)d_in[9];
    const float* Wfc = (const float*)d_in[10];
    const float* bfc = (const float*)d_in[11];
    float* out = (float*)d_out;

    char* p = (char*)d_ws;
    auto alloc = [&](size_t bytes) {
        char* r = p;
        p += (bytes + 255) & ~size_t(255);
        return r;
    };
    unsigned short* xb   = (unsigned short*)alloc((size_t)N_NODES * F_INPUT * 2);
    unsigned short* h0   = (unsigned short*)alloc((size_t)N_NODES * F_INPUT * 2);
    unsigned short* t    = (unsigned short*)alloc((size_t)N_NODES * HID * 2);
    unsigned short* g    = (unsigned short*)alloc((size_t)N_NODES * HID * 2);
    unsigned short* W1aT = (unsigned short*)alloc(128 * 96 * 2);
    unsigned short* W2aT = (unsigned short*)alloc(128 * 128 * 2);
    unsigned short* W1bT = (unsigned short*)alloc(128 * 128 * 2);
    unsigned short* WcT  = (unsigned short*)alloc(64 * 128 * 2);
    float* bc            = (float*)alloc(64 * 4);
    int* binCursor       = (int*)alloc(NBIN * 4);                               // 784B
    unsigned int* binBuf = (unsigned int*)alloc((size_t)NBIN * CAPB * 4);       // 3.6MB
    unsigned short* bucket = (unsigned short*)alloc((size_t)N_NODES * REC * 2); // 6.4MB

    const int nb4 = (N_NODES + 3) / 4;  // 12500
    const int mb = (N_NODES + 63) / 64; // 782

    // zero bin cursors (tiny)
    hipMemsetAsync(binCursor, 0, NBIN * sizeof(int), stream);

    // prep: radix pass1 (first) + x->bf16 + fuse_w + weight transposes
    prep_all<<<PA_END, 256, 0, stream>>>(x, W1a, W2a, W1b, W2b, b2b, Wfc, bfc, ei,
                                         W1aT, W2aT, W1bT, WcT, bc, binCursor, binBuf, xb);

    // radix pass2: bins -> bucket records (writes counters; no bucket memset)
    radix2<<<NBIN, 1024, 0, stream>>>(binCursor, binBuf, bucket);

    // GIN layer 1: gather on bf16 x, then fused MLP (relu between, relu after)
    gather_bf<F_INPUT><<<nb4, 256, 0, stream>>>(xb, bucket, h0);
    mlp_fused<96, 8, 128, true, true><<<mb, 256, 0, stream>>>(h0, W1aT, b1a, W2aT, b2a, t,
                                                              N_NODES);

    // GIN layer 2: gather, then fused MLP (relu between, final linear folded W2b@Wfc)
    gather_bf<HID><<<nb4, 256, 0, stream>>>(t, bucket, g);
    mlp_fused<128, 4, 40, false, false><<<mb, 256, 0, stream>>>(g, W1bT, b1b, WcT, bc, out,
                                                                N_NODES);
}